// Round 5
// baseline (571.598 us; speedup 1.0000x reference)
//
#include <hip/hip_runtime.h>
#include <cstdint>
#include <cstddef>

#define NEG_SLOPE 0.2f

typedef __attribute__((ext_vector_type(8))) short short8;
typedef __attribute__((ext_vector_type(4))) float f32x4;

__device__ __forceinline__ float lrelu(float v) { return v > 0.0f ? v : NEG_SLOPE * v; }

__device__ __forceinline__ unsigned short f2bf(float f) {
  unsigned u = __float_as_uint(f);
  unsigned r = (u + 0x7fff + ((u >> 16) & 1)) >> 16;  // RNE
  return (unsigned short)r;
}
__device__ __forceinline__ float bf2f(unsigned short u) {
  return __uint_as_float((unsigned)u << 16);
}
__device__ __forceinline__ unsigned pack2bf(float a, float b) {
  return (unsigned)f2bf(a) | ((unsigned)f2bf(b) << 16);
}

// ---- prep: both W converts + cnt zero in one dispatch ----
__global__ __launch_bounds__(256) void prep(const float* __restrict__ W1,
                                            const float* __restrict__ W2,
                                            unsigned short* __restrict__ WT1,
                                            unsigned short* __restrict__ WT2,
                                            int* __restrict__ cnt, int N) {
  int i = blockIdx.x * 256 + threadIdx.x;
  if (i < 16384) {
    int n = i >> 7, k = i & 127;
    WT1[i] = f2bf(W1[k * 128 + n]);
  } else if (i < 32768) {
    int j = i - 16384;
    int n = j >> 7, k = j & 127;
    WT2[j] = f2bf(W2[k * 128 + n]);
  }
  if (i < N) cnt[i] = 0;
}

// ---- MFMA GEMM + fused alpha epilogue ----
// Ybf[N,128](bf16) = X[N,128] @ W;  AS/AD[n(,h)] = dot(h_row, a_src/a_dst)
// X is fp32 (BF16IN=false) or bf16 (BF16IN=true).
// 64 rows/block, 256 threads = 4 waves; wave w does rows 16w..16w+15, all 8 col tiles.
template <int H, bool BF16IN>
__global__ __launch_bounds__(256) void gemm_mfma(const void* __restrict__ Xv,
                                                 const unsigned short* __restrict__ WT,
                                                 unsigned short* __restrict__ Ybf,
                                                 const float* __restrict__ Asrc,
                                                 const float* __restrict__ Adst,
                                                 float* __restrict__ AS,
                                                 float* __restrict__ AD, int N) {
  __shared__ unsigned short xs[64 * 136];   // X tile bf16, stride 136 (272B, 16B-aligned)
  __shared__ unsigned short wsh[128 * 136]; // W^T bf16 [n][k]
  __shared__ float ash[128];                // alpha weights (H*C == 128 in both layers)
  __shared__ float adh[128];
  const int tid = threadIdx.x;
  const int rowBase = blockIdx.x * 64;
  const int rowsHere = min(64, N - rowBase);

  // stage alpha weights
  if (tid < 128) ash[tid] = Asrc[tid];
  else adh[tid - 128] = Adst[tid - 128];

  // stage WT -> LDS: 128x128 bf16 = 2048 16B-chunks
#pragma unroll
  for (int it = 0; it < 8; ++it) {
    int idx = it * 256 + tid;
    int n = idx >> 4, k16 = idx & 15;
    *(uint4*)(wsh + n * 136 + k16 * 8) = *(const uint4*)(WT + (size_t)n * 128 + k16 * 8);
  }
  // stage X: 64x128 (64 rows x 16 chunks of 16B)
  if constexpr (BF16IN) {
    const unsigned short* Xb = (const unsigned short*)Xv;
#pragma unroll
    for (int it = 0; it < 4; ++it) {
      int idx = it * 256 + tid;
      int r = idx >> 4, c8 = idx & 15;
      uint4 v = make_uint4(0, 0, 0, 0);
      if (r < rowsHere) v = *(const uint4*)(Xb + (size_t)(rowBase + r) * 128 + c8 * 8);
      *(uint4*)(xs + r * 136 + c8 * 8) = v;
    }
  } else {
    const float* Xf = (const float*)Xv;
#pragma unroll
    for (int it = 0; it < 8; ++it) {
      int idx = it * 256 + tid;
      int r = idx >> 5, c4 = idx & 31;
      float4 v = make_float4(0.f, 0.f, 0.f, 0.f);
      if (r < rowsHere) v = *(const float4*)(Xf + (size_t)(rowBase + r) * 128 + c4 * 4);
      ushort4 bv;
      bv.x = f2bf(v.x); bv.y = f2bf(v.y); bv.z = f2bf(v.z); bv.w = f2bf(v.w);
      *(ushort4*)(xs + r * 136 + c4 * 4) = bv;
    }
  }
  __syncthreads();

  const int lane = tid & 63;
  const int w = tid >> 6;
  const int m15 = lane & 15;
  const int quad = lane >> 4;
  f32x4 acc[8];
#pragma unroll
  for (int t = 0; t < 8; ++t) acc[t] = (f32x4){0.f, 0.f, 0.f, 0.f};

#pragma unroll
  for (int k0 = 0; k0 < 128; k0 += 32) {
    short8 a = *(const short8*)(xs + (16 * w + m15) * 136 + k0 + quad * 8);
#pragma unroll
    for (int t = 0; t < 8; ++t) {
      short8 b = *(const short8*)(wsh + (t * 16 + m15) * 136 + k0 + quad * 8);
      acc[t] = __builtin_amdgcn_mfma_f32_16x16x32_bf16(a, b, acc[t], 0, 0, 0);
    }
  }

  // epilogue: acc -> LDS (bf16) -> coalesced global store
  __syncthreads();
#pragma unroll
  for (int t = 0; t < 8; ++t) {
#pragma unroll
    for (int r = 0; r < 4; ++r) {
      int row = 16 * w + quad * 4 + r;  // C/D layout: col=lane&15, row=quad*4+reg
      xs[row * 136 + t * 16 + m15] = f2bf(acc[t][r]);
    }
  }
  __syncthreads();
#pragma unroll
  for (int it = 0; it < 4; ++it) {
    int idx = it * 256 + tid;  // 64 rows x 16 chunks of 16B
    int r = idx >> 4, c8 = idx & 15;
    if (r < rowsHere)
      *(uint4*)(Ybf + (size_t)(rowBase + r) * 128 + c8 * 8) = *(const uint4*)(xs + r * 136 + c8 * 8);
  }

  // fused alphas: 4 threads/row, 32 channels each (reads xs, valid after barrier above)
  {
    const int r = tid >> 2;
    const int part = tid & 3;
    if (r < rowsHere) {
      const unsigned short* hp = xs + r * 136 + part * 32;
      float as = 0.f, ad = 0.f;
#pragma unroll
      for (int c4 = 0; c4 < 4; ++c4) {
        uint4 hw = *(const uint4*)(hp + c4 * 8);
        unsigned wds[4] = {hw.x, hw.y, hw.z, hw.w};
#pragma unroll
        for (int k = 0; k < 4; ++k) {
          const int c = part * 32 + c4 * 8 + k * 2;
          float v0 = bf2f((unsigned short)wds[k]);
          float v1 = bf2f((unsigned short)(wds[k] >> 16));
          as += v0 * ash[c] + v1 * ash[c + 1];
          ad += v0 * adh[c] + v1 * adh[c + 1];
        }
      }
      if (H == 4) {
        AS[(size_t)(rowBase + r) * 4 + part] = as;
        AD[(size_t)(rowBase + r) * 4 + part] = ad;
      } else {
        as += __shfl_xor(as, 1, 4);
        as += __shfl_xor(as, 2, 4);
        ad += __shfl_xor(ad, 1, 4);
        ad += __shfl_xor(ad, 2, 4);
        if (part == 0) { AS[rowBase + r] = as; AD[rowBase + r] = ad; }
      }
    }
  }
}

// ================= CSR build =================
__global__ __launch_bounds__(256) void csr_count(const int* __restrict__ ei, int E, int Etot,
                                                 int* __restrict__ cnt) {
  int e = blockIdx.x * 256 + threadIdx.x;
  if (e >= Etot) return;
  int d = (e < E) ? ei[E + e] : (e - E);
  atomicAdd(&cnt[d], 1);
}

__global__ __launch_bounds__(256) void scan_blocks(const int* __restrict__ cnt,
                                                   int* __restrict__ rowStart,
                                                   int* __restrict__ blockSums, int N) {
  __shared__ int sh[256];
  const int tid = threadIdx.x;
  const int i = blockIdx.x * 256 + tid;
  int v = (i < N) ? cnt[i] : 0;
  sh[tid] = v;
  __syncthreads();
  for (int o = 1; o < 256; o <<= 1) {
    int t = (tid >= o) ? sh[tid - o] : 0;
    __syncthreads();
    sh[tid] += t;
    __syncthreads();
  }
  if (i < N) rowStart[i] = sh[tid] - v;
  if (tid == 255) blockSums[blockIdx.x] = sh[255];
}

__global__ __launch_bounds__(256) void scan_sums(int* __restrict__ bs, int nb) {
  __shared__ int sh[256];
  __shared__ int carryS;
  const int tid = threadIdx.x;
  if (tid == 0) carryS = 0;
  __syncthreads();
  for (int c = 0; c < nb; c += 256) {
    int i = c + tid;
    int v = (i < nb) ? bs[i] : 0;
    sh[tid] = v;
    __syncthreads();
    for (int o = 1; o < 256; o <<= 1) {
      int t = (tid >= o) ? sh[tid - o] : 0;
      __syncthreads();
      sh[tid] += t;
      __syncthreads();
    }
    int carry = carryS;
    if (i < nb) bs[i] = carry + sh[tid] - v;
    int total = sh[255];
    __syncthreads();
    if (tid == 0) carryS = carry + total;
    __syncthreads();
  }
}

__global__ __launch_bounds__(256) void add_offsets(int* __restrict__ rowStart,
                                                   const int* __restrict__ bs,
                                                   int* __restrict__ cursor, int N, int Etot) {
  int i = blockIdx.x * 256 + threadIdx.x;
  if (i == 0) rowStart[N] = Etot;
  if (i >= N) return;
  int r = rowStart[i] + bs[i >> 8];
  rowStart[i] = r;
  cursor[i] = r;
}

// XCD-partitioned scatter: perf-only heuristic, G16-safe.
#define SCAT_CHUNK 2048
__global__ __launch_bounds__(256) void csr_scatter_x(const int* __restrict__ ei, int E, int Etot,
                                                     int* __restrict__ cursor,
                                                     int* __restrict__ srcS, int nper) {
  const int xcd = blockIdx.x & 7;
  const int lo = xcd * nper;
  const int hi = lo + nper;
  const int e0 = (blockIdx.x >> 3) * SCAT_CHUNK + threadIdx.x;
#pragma unroll
  for (int it = 0; it < SCAT_CHUNK / 256; ++it) {
    int e = e0 + it * 256;
    if (e < Etot) {
      int d = (e < E) ? ei[E + e] : (e - E);
      if (d >= lo && d < hi) {
        int s = (e < E) ? ei[e] : d;
        int pos = atomicAdd(&cursor[d], 1);
        srcS[pos] = s;
      }
    }
  }
}

// ==== fused per-node softmax + bf16 gather-aggregate ====
// Round 10 restructure: ONE WAVE (64 lanes) PER NODE, 2 channels/lane.
//  - softmax computed WITHOUT max-shift (values bounded; softmax shift-invariant):
//    deletes the whole phase-A sweep and all cross-lane reduces (every lane sees
//    every edge, so den accumulates completely per-lane).
//  - 8-deep double-buffered gather (dword/lane) costs ~32 VGPR of buffers; total
//    stays under the 64-VGPR occupancy cliff -> 8 waves/SIMD (launch_bounds 256,8).
//  - loop trips are wave-uniform (no intra-wave divergence).
template <int H, bool OUTBF>
__global__ __launch_bounds__(256, 8) void gat_node(
    const int* __restrict__ rowStart, const int* __restrict__ srcS,
    const float* __restrict__ AS, const float* __restrict__ AD,
    const unsigned short* __restrict__ Hbf, const float* __restrict__ B,
    void* __restrict__ Out, int N) {
  const int wid = threadIdx.x >> 6;
  const int n = blockIdx.x * 4 + wid;
  if (n >= N) return;
  const int lane = threadIdx.x & 63;
  const int c0 = lane * 2;                       // channel pair [c0, c0+1]
  const int myh = (H == 4) ? (lane >> 4) : 0;    // head = c0/32
  const int beg = rowStart[n];
  const int end = rowStart[n + 1];
  const float ad_my = (H == 4) ? AD[(size_t)n * 4 + myh] : AD[n];

  float den = 0.f, acc0 = 0.f, acc1 = 0.f;

  auto ISSUE = [&](int ib, unsigned (&hw)[8], float (&av)[8]) {
#pragma unroll
    for (int q = 0; q < 8; ++q) {
      int idx = ib + q;
      const int s = srcS[idx < end ? idx : beg];  // srcS[beg] valid (self-loop => deg>=1)
      hw[q] = *(const unsigned*)(Hbf + (size_t)s * 128 + c0);
      av[q] = (H == 4) ? AS[(size_t)s * 4 + myh] : AS[s];
    }
  };
  auto CONSUME = [&](int ib, unsigned (&hw)[8], float (&av)[8]) {
#pragma unroll
    for (int q = 0; q < 8; ++q) {
      float p = (ib + q < end) ? __expf(lrelu(av[q] + ad_my)) : 0.f;
      den += p;
      acc0 += bf2f((unsigned short)hw[q]) * p;
      acc1 += bf2f((unsigned short)(hw[q] >> 16)) * p;
    }
  };

  unsigned hwA[8], hwB[8];
  float avA[8], avB[8];
  int i = beg;
  ISSUE(i, hwA, avA);
  for (;;) {
    int inext = i + 8;
    if (inext < end) ISSUE(inext, hwB, avB);
    CONSUME(i, hwA, avA);
    i = inext;
    if (i >= end) break;
    inext = i + 8;
    if (inext < end) ISSUE(inext, hwA, avA);
    CONSUME(i, hwB, avB);
    i = inext;
    if (i >= end) break;
  }

  const float inv = 1.0f / (den + 1e-16f);
  const float2 bv = *(const float2*)(B + c0);
  const float o0 = acc0 * inv + bv.x;
  const float o1 = acc1 * inv + bv.y;
  if constexpr (OUTBF) {
    *((unsigned*)Out + (size_t)n * 64 + lane) = pack2bf(o0, o1);
  } else {
    *(float2*)((float*)Out + (size_t)n * 128 + c0) = make_float2(o0, o1);
  }
}

extern "C" void kernel_launch(void* const* d_in, const int* in_sizes, int n_in,
                              void* d_out, int out_size, void* d_ws, size_t ws_size,
                              hipStream_t stream) {
  const float* x    = (const float*)d_in[0];
  const int*   ei   = (const int*)d_in[1];
  const float* W1   = (const float*)d_in[2];
  const float* as1w = (const float*)d_in[3];
  const float* ad1w = (const float*)d_in[4];
  const float* b1   = (const float*)d_in[5];
  const float* W2   = (const float*)d_in[6];
  const float* as2w = (const float*)d_in[7];
  const float* ad2w = (const float*)d_in[8];
  const float* b2   = (const float*)d_in[9];

  const int N = in_sizes[0] / 128;
  const int E = in_sizes[1] / 2;
  const int Etot = E + N;
  const int nb = (N + 255) / 256;

  char* ws = (char*)d_ws;
  size_t off = 0;
  auto alloc = [&](size_t bytes) -> void* {
    void* p = ws + off;
    off = (off + bytes + 255) & ~(size_t)255;
    return p;
  };
  unsigned short* Hbf   = (unsigned short*)alloc((size_t)N * 128 * 2);
  unsigned short* out1b = (unsigned short*)alloc((size_t)N * 128 * 2);
  float* AS1  = (float*)alloc((size_t)N * 4 * 4);
  float* AD1  = (float*)alloc((size_t)N * 4 * 4);
  float* AS2  = (float*)alloc((size_t)N * 4);
  float* AD2  = (float*)alloc((size_t)N * 4);
  unsigned short* WT1 = (unsigned short*)alloc(128 * 128 * 2);
  unsigned short* WT2 = (unsigned short*)alloc(128 * 128 * 2);
  int*   cnt      = (int*)alloc((size_t)N * 4);
  int*   rowStart = (int*)alloc((size_t)(N + 1) * 4);
  int*   cursor   = (int*)alloc((size_t)N * 4);
  int*   blockSums= (int*)alloc((size_t)nb * 4);
  int*   srcS     = (int*)alloc((size_t)Etot * 4);

  // ---- prep: W converts + cnt zero (one dispatch) ----
  const int prepBlocks = (max(32768, N) + 255) / 256;
  prep<<<prepBlocks, 256, 0, stream>>>(W1, W2, WT1, WT2, cnt, N);

  // ---- CSR build (once, shared by both layers) ----
  const int ebBlocks = (Etot + 255) / 256;
  csr_count<<<ebBlocks, 256, 0, stream>>>(ei, E, Etot, cnt);
  scan_blocks<<<nb, 256, 0, stream>>>(cnt, rowStart, blockSums, N);
  scan_sums<<<1, 256, 0, stream>>>(blockSums, nb);
  add_offsets<<<nb, 256, 0, stream>>>(rowStart, blockSums, cursor, N, Etot);
  const int nper = (N + 7) / 8;
  const int scatBlocks = 8 * ((Etot + SCAT_CHUNK - 1) / SCAT_CHUNK);
  csr_scatter_x<<<scatBlocks, 256, 0, stream>>>(ei, E, Etot, cursor, srcS, nper);

  const int gemmBlocks = (N + 63) / 64;
  const int nodeBlocks = (N + 3) / 4;

  // ---- layer 1 (H=4, C=32): GEMM with fused alphas; gat writes bf16 ----
  gemm_mfma<4, false><<<gemmBlocks, 256, 0, stream>>>(x, WT1, Hbf, as1w, ad1w, AS1, AD1, N);
  gat_node<4, true><<<nodeBlocks, 256, 0, stream>>>(rowStart, srcS, AS1, AD1, Hbf, b1, out1b, N);

  // ---- layer 2 (H=1, C=128): GEMM reads bf16 input directly ----
  gemm_mfma<1, true><<<gemmBlocks, 256, 0, stream>>>(out1b, WT2, Hbf, as2w, ad2w, AS2, AD2, N);
  gat_node<1, false><<<nodeBlocks, 256, 0, stream>>>(rowStart, srcS, AS2, AD2, Hbf, b2, d_out, N);
}

// Round 6
// 447.731 us; speedup vs baseline: 1.2767x; 1.2767x over previous
//
#include <hip/hip_runtime.h>
#include <cstdint>
#include <cstddef>

#define NEG_SLOPE 0.2f

typedef __attribute__((ext_vector_type(8))) short short8;
typedef __attribute__((ext_vector_type(4))) float f32x4;

__device__ __forceinline__ float lrelu(float v) { return v > 0.0f ? v : NEG_SLOPE * v; }

__device__ __forceinline__ unsigned short f2bf(float f) {
  unsigned u = __float_as_uint(f);
  unsigned r = (u + 0x7fff + ((u >> 16) & 1)) >> 16;  // RNE
  return (unsigned short)r;
}
__device__ __forceinline__ float bf2f(unsigned short u) {
  return __uint_as_float((unsigned)u << 16);
}
__device__ __forceinline__ unsigned pack2bf(float a, float b) {
  return (unsigned)f2bf(a) | ((unsigned)f2bf(b) << 16);
}

// ---- prep: both W converts + cnt zero in one dispatch ----
__global__ __launch_bounds__(256) void prep(const float* __restrict__ W1,
                                            const float* __restrict__ W2,
                                            unsigned short* __restrict__ WT1,
                                            unsigned short* __restrict__ WT2,
                                            int* __restrict__ cnt, int N) {
  int i = blockIdx.x * 256 + threadIdx.x;
  if (i < 16384) {
    int n = i >> 7, k = i & 127;
    WT1[i] = f2bf(W1[k * 128 + n]);
  } else if (i < 32768) {
    int j = i - 16384;
    int n = j >> 7, k = j & 127;
    WT2[j] = f2bf(W2[k * 128 + n]);
  }
  if (i < N) cnt[i] = 0;
}

// ---- MFMA GEMM + fused alpha epilogue ----
// Ybf[N,128](bf16) = X[N,128] @ W;  AS/AD[n(,h)] = dot(h_row, a_src/a_dst)
// X is fp32 (BF16IN=false) or bf16 (BF16IN=true).
// 64 rows/block, 256 threads = 4 waves; wave w does rows 16w..16w+15, all 8 col tiles.
template <int H, bool BF16IN>
__global__ __launch_bounds__(256) void gemm_mfma(const void* __restrict__ Xv,
                                                 const unsigned short* __restrict__ WT,
                                                 unsigned short* __restrict__ Ybf,
                                                 const float* __restrict__ Asrc,
                                                 const float* __restrict__ Adst,
                                                 float* __restrict__ AS,
                                                 float* __restrict__ AD, int N) {
  __shared__ unsigned short xs[64 * 136];   // X tile bf16, stride 136 (272B, 16B-aligned)
  __shared__ unsigned short wsh[128 * 136]; // W^T bf16 [n][k]
  __shared__ float ash[128];                // alpha weights (H*C == 128 in both layers)
  __shared__ float adh[128];
  const int tid = threadIdx.x;
  const int rowBase = blockIdx.x * 64;
  const int rowsHere = min(64, N - rowBase);

  // stage alpha weights
  if (tid < 128) ash[tid] = Asrc[tid];
  else adh[tid - 128] = Adst[tid - 128];

  // stage WT -> LDS: 128x128 bf16 = 2048 16B-chunks
#pragma unroll
  for (int it = 0; it < 8; ++it) {
    int idx = it * 256 + tid;
    int n = idx >> 4, k16 = idx & 15;
    *(uint4*)(wsh + n * 136 + k16 * 8) = *(const uint4*)(WT + (size_t)n * 128 + k16 * 8);
  }
  // stage X: 64x128 (64 rows x 16 chunks of 16B)
  if constexpr (BF16IN) {
    const unsigned short* Xb = (const unsigned short*)Xv;
#pragma unroll
    for (int it = 0; it < 4; ++it) {
      int idx = it * 256 + tid;
      int r = idx >> 4, c8 = idx & 15;
      uint4 v = make_uint4(0, 0, 0, 0);
      if (r < rowsHere) v = *(const uint4*)(Xb + (size_t)(rowBase + r) * 128 + c8 * 8);
      *(uint4*)(xs + r * 136 + c8 * 8) = v;
    }
  } else {
    const float* Xf = (const float*)Xv;
#pragma unroll
    for (int it = 0; it < 8; ++it) {
      int idx = it * 256 + tid;
      int r = idx >> 5, c4 = idx & 31;
      float4 v = make_float4(0.f, 0.f, 0.f, 0.f);
      if (r < rowsHere) v = *(const float4*)(Xf + (size_t)(rowBase + r) * 128 + c4 * 4);
      ushort4 bv;
      bv.x = f2bf(v.x); bv.y = f2bf(v.y); bv.z = f2bf(v.z); bv.w = f2bf(v.w);
      *(ushort4*)(xs + r * 136 + c4 * 4) = bv;
    }
  }
  __syncthreads();

  const int lane = tid & 63;
  const int w = tid >> 6;
  const int m15 = lane & 15;
  const int quad = lane >> 4;
  f32x4 acc[8];
#pragma unroll
  for (int t = 0; t < 8; ++t) acc[t] = (f32x4){0.f, 0.f, 0.f, 0.f};

#pragma unroll
  for (int k0 = 0; k0 < 128; k0 += 32) {
    short8 a = *(const short8*)(xs + (16 * w + m15) * 136 + k0 + quad * 8);
#pragma unroll
    for (int t = 0; t < 8; ++t) {
      short8 b = *(const short8*)(wsh + (t * 16 + m15) * 136 + k0 + quad * 8);
      acc[t] = __builtin_amdgcn_mfma_f32_16x16x32_bf16(a, b, acc[t], 0, 0, 0);
    }
  }

  // epilogue: acc -> LDS (bf16) -> coalesced global store
  __syncthreads();
#pragma unroll
  for (int t = 0; t < 8; ++t) {
#pragma unroll
    for (int r = 0; r < 4; ++r) {
      int row = 16 * w + quad * 4 + r;  // C/D layout: col=lane&15, row=quad*4+reg
      xs[row * 136 + t * 16 + m15] = f2bf(acc[t][r]);
    }
  }
  __syncthreads();
#pragma unroll
  for (int it = 0; it < 4; ++it) {
    int idx = it * 256 + tid;  // 64 rows x 16 chunks of 16B
    int r = idx >> 4, c8 = idx & 15;
    if (r < rowsHere)
      *(uint4*)(Ybf + (size_t)(rowBase + r) * 128 + c8 * 8) = *(const uint4*)(xs + r * 136 + c8 * 8);
  }

  // fused alphas: 4 threads/row, 32 channels each (reads xs, valid after barrier above)
  {
    const int r = tid >> 2;
    const int part = tid & 3;
    if (r < rowsHere) {
      const unsigned short* hp = xs + r * 136 + part * 32;
      float as = 0.f, ad = 0.f;
#pragma unroll
      for (int c4 = 0; c4 < 4; ++c4) {
        uint4 hw = *(const uint4*)(hp + c4 * 8);
        unsigned wds[4] = {hw.x, hw.y, hw.z, hw.w};
#pragma unroll
        for (int k = 0; k < 4; ++k) {
          const int c = part * 32 + c4 * 8 + k * 2;
          float v0 = bf2f((unsigned short)wds[k]);
          float v1 = bf2f((unsigned short)(wds[k] >> 16));
          as += v0 * ash[c] + v1 * ash[c + 1];
          ad += v0 * adh[c] + v1 * adh[c + 1];
        }
      }
      if (H == 4) {
        AS[(size_t)(rowBase + r) * 4 + part] = as;
        AD[(size_t)(rowBase + r) * 4 + part] = ad;
      } else {
        as += __shfl_xor(as, 1, 4);
        as += __shfl_xor(as, 2, 4);
        ad += __shfl_xor(ad, 1, 4);
        ad += __shfl_xor(ad, 2, 4);
        if (part == 0) { AS[rowBase + r] = as; AD[rowBase + r] = ad; }
      }
    }
  }
}

// ================= CSR build =================
__global__ __launch_bounds__(256) void csr_count(const int* __restrict__ ei, int E, int Etot,
                                                 int* __restrict__ cnt) {
  int e = blockIdx.x * 256 + threadIdx.x;
  if (e >= Etot) return;
  int d = (e < E) ? ei[E + e] : (e - E);
  atomicAdd(&cnt[d], 1);
}

__global__ __launch_bounds__(256) void scan_blocks(const int* __restrict__ cnt,
                                                   int* __restrict__ rowStart,
                                                   int* __restrict__ blockSums, int N) {
  __shared__ int sh[256];
  const int tid = threadIdx.x;
  const int i = blockIdx.x * 256 + tid;
  int v = (i < N) ? cnt[i] : 0;
  sh[tid] = v;
  __syncthreads();
  for (int o = 1; o < 256; o <<= 1) {
    int t = (tid >= o) ? sh[tid - o] : 0;
    __syncthreads();
    sh[tid] += t;
    __syncthreads();
  }
  if (i < N) rowStart[i] = sh[tid] - v;
  if (tid == 255) blockSums[blockIdx.x] = sh[255];
}

__global__ __launch_bounds__(256) void scan_sums(int* __restrict__ bs, int nb) {
  __shared__ int sh[256];
  __shared__ int carryS;
  const int tid = threadIdx.x;
  if (tid == 0) carryS = 0;
  __syncthreads();
  for (int c = 0; c < nb; c += 256) {
    int i = c + tid;
    int v = (i < nb) ? bs[i] : 0;
    sh[tid] = v;
    __syncthreads();
    for (int o = 1; o < 256; o <<= 1) {
      int t = (tid >= o) ? sh[tid - o] : 0;
      __syncthreads();
      sh[tid] += t;
      __syncthreads();
    }
    int carry = carryS;
    if (i < nb) bs[i] = carry + sh[tid] - v;
    int total = sh[255];
    __syncthreads();
    if (tid == 0) carryS = carry + total;
    __syncthreads();
  }
}

__global__ __launch_bounds__(256) void add_offsets(int* __restrict__ rowStart,
                                                   const int* __restrict__ bs,
                                                   int* __restrict__ cursor, int N, int Etot) {
  int i = blockIdx.x * 256 + threadIdx.x;
  if (i == 0) rowStart[N] = Etot;
  if (i >= N) return;
  int r = rowStart[i] + bs[i >> 8];
  rowStart[i] = r;
  cursor[i] = r;
}

// XCD-partitioned scatter: perf-only heuristic, G16-safe.
#define SCAT_CHUNK 2048
__global__ __launch_bounds__(256) void csr_scatter_x(const int* __restrict__ ei, int E, int Etot,
                                                     int* __restrict__ cursor,
                                                     int* __restrict__ srcS, int nper) {
  const int xcd = blockIdx.x & 7;
  const int lo = xcd * nper;
  const int hi = lo + nper;
  const int e0 = (blockIdx.x >> 3) * SCAT_CHUNK + threadIdx.x;
#pragma unroll
  for (int it = 0; it < SCAT_CHUNK / 256; ++it) {
    int e = e0 + it * 256;
    if (e < Etot) {
      int d = (e < E) ? ei[E + e] : (e - E);
      if (d >= lo && d < hi) {
        int s = (e < E) ? ei[e] : d;
        int pos = atomicAdd(&cursor[d], 1);
        srcS[pos] = s;
      }
    }
  }
}

// ==== fused per-node softmax + bf16 gather-aggregate ====
// ONE WAVE (64 lanes) PER NODE, 2 channels/lane; no max-shift (bounded alphas,
// softmax shift-invariant) -> single edge sweep, no cross-lane reduces.
// ROUND-11 FIX: launch_bounds (256,8) forced VGPR=32 -> the hwA/hwB/avA/avB double
// buffers spilled to scratch (WRITE_SIZE 25->252MB, hbm_bytes 2.1x, 2x duration).
// Relax to (256,4): compiler lands ~56-64 VGPR, no spill, still 8 waves/SIMD if <=64.
// beg/end hoisted to SGPR via readfirstlane (wave-uniform: all lanes share n).
template <int H, bool OUTBF>
__global__ __launch_bounds__(256, 4) void gat_node(
    const int* __restrict__ rowStart, const int* __restrict__ srcS,
    const float* __restrict__ AS, const float* __restrict__ AD,
    const unsigned short* __restrict__ Hbf, const float* __restrict__ B,
    void* __restrict__ Out, int N) {
  const int wid = threadIdx.x >> 6;
  const int n = blockIdx.x * 4 + wid;
  if (n >= N) return;
  const int lane = threadIdx.x & 63;
  const int c0 = lane * 2;                       // channel pair [c0, c0+1]
  const int myh = (H == 4) ? (lane >> 4) : 0;    // head = c0/32
  const int beg = __builtin_amdgcn_readfirstlane(rowStart[n]);
  const int end = __builtin_amdgcn_readfirstlane(rowStart[n + 1]);
  const float ad_my = (H == 4) ? AD[(size_t)n * 4 + myh] : AD[n];

  float den = 0.f, acc0 = 0.f, acc1 = 0.f;

  auto ISSUE = [&](int ib, unsigned (&hw)[8], float (&av)[8]) {
#pragma unroll
    for (int q = 0; q < 8; ++q) {
      int idx = ib + q;
      const int s = srcS[idx < end ? idx : beg];  // srcS[beg] valid (self-loop => deg>=1)
      hw[q] = *(const unsigned*)(Hbf + (size_t)s * 128 + c0);
      av[q] = (H == 4) ? AS[(size_t)s * 4 + myh] : AS[s];
    }
  };
  auto CONSUME = [&](int ib, unsigned (&hw)[8], float (&av)[8]) {
#pragma unroll
    for (int q = 0; q < 8; ++q) {
      float p = (ib + q < end) ? __expf(lrelu(av[q] + ad_my)) : 0.f;
      den += p;
      acc0 += bf2f((unsigned short)hw[q]) * p;
      acc1 += bf2f((unsigned short)(hw[q] >> 16)) * p;
    }
  };

  unsigned hwA[8], hwB[8];
  float avA[8], avB[8];
  int i = beg;
  ISSUE(i, hwA, avA);
  for (;;) {
    int inext = i + 8;
    if (inext < end) ISSUE(inext, hwB, avB);
    CONSUME(i, hwA, avA);
    i = inext;
    if (i >= end) break;
    inext = i + 8;
    if (inext < end) ISSUE(inext, hwA, avA);
    CONSUME(i, hwB, avB);
    i = inext;
    if (i >= end) break;
  }

  const float inv = 1.0f / (den + 1e-16f);
  const float2 bv = *(const float2*)(B + c0);
  const float o0 = acc0 * inv + bv.x;
  const float o1 = acc1 * inv + bv.y;
  if constexpr (OUTBF) {
    *((unsigned*)Out + (size_t)n * 64 + lane) = pack2bf(o0, o1);
  } else {
    *(float2*)((float*)Out + (size_t)n * 128 + c0) = make_float2(o0, o1);
  }
}

extern "C" void kernel_launch(void* const* d_in, const int* in_sizes, int n_in,
                              void* d_out, int out_size, void* d_ws, size_t ws_size,
                              hipStream_t stream) {
  const float* x    = (const float*)d_in[0];
  const int*   ei   = (const int*)d_in[1];
  const float* W1   = (const float*)d_in[2];
  const float* as1w = (const float*)d_in[3];
  const float* ad1w = (const float*)d_in[4];
  const float* b1   = (const float*)d_in[5];
  const float* W2   = (const float*)d_in[6];
  const float* as2w = (const float*)d_in[7];
  const float* ad2w = (const float*)d_in[8];
  const float* b2   = (const float*)d_in[9];

  const int N = in_sizes[0] / 128;
  const int E = in_sizes[1] / 2;
  const int Etot = E + N;
  const int nb = (N + 255) / 256;

  char* ws = (char*)d_ws;
  size_t off = 0;
  auto alloc = [&](size_t bytes) -> void* {
    void* p = ws + off;
    off = (off + bytes + 255) & ~(size_t)255;
    return p;
  };
  unsigned short* Hbf   = (unsigned short*)alloc((size_t)N * 128 * 2);
  unsigned short* out1b = (unsigned short*)alloc((size_t)N * 128 * 2);
  float* AS1  = (float*)alloc((size_t)N * 4 * 4);
  float* AD1  = (float*)alloc((size_t)N * 4 * 4);
  float* AS2  = (float*)alloc((size_t)N * 4);
  float* AD2  = (float*)alloc((size_t)N * 4);
  unsigned short* WT1 = (unsigned short*)alloc(128 * 128 * 2);
  unsigned short* WT2 = (unsigned short*)alloc(128 * 128 * 2);
  int*   cnt      = (int*)alloc((size_t)N * 4);
  int*   rowStart = (int*)alloc((size_t)(N + 1) * 4);
  int*   cursor   = (int*)alloc((size_t)N * 4);
  int*   blockSums= (int*)alloc((size_t)nb * 4);
  int*   srcS     = (int*)alloc((size_t)Etot * 4);

  // ---- prep: W converts + cnt zero (one dispatch) ----
  const int prepBlocks = (max(32768, N) + 255) / 256;
  prep<<<prepBlocks, 256, 0, stream>>>(W1, W2, WT1, WT2, cnt, N);

  // ---- CSR build (once, shared by both layers) ----
  const int ebBlocks = (Etot + 255) / 256;
  csr_count<<<ebBlocks, 256, 0, stream>>>(ei, E, Etot, cnt);
  scan_blocks<<<nb, 256, 0, stream>>>(cnt, rowStart, blockSums, N);
  scan_sums<<<1, 256, 0, stream>>>(blockSums, nb);
  add_offsets<<<nb, 256, 0, stream>>>(rowStart, blockSums, cursor, N, Etot);
  const int nper = (N + 7) / 8;
  const int scatBlocks = 8 * ((Etot + SCAT_CHUNK - 1) / SCAT_CHUNK);
  csr_scatter_x<<<scatBlocks, 256, 0, stream>>>(ei, E, Etot, cursor, srcS, nper);

  const int gemmBlocks = (N + 63) / 64;
  const int nodeBlocks = (N + 3) / 4;

  // ---- layer 1 (H=4, C=32): GEMM with fused alphas; gat writes bf16 ----
  gemm_mfma<4, false><<<gemmBlocks, 256, 0, stream>>>(x, WT1, Hbf, as1w, ad1w, AS1, AD1, N);
  gat_node<4, true><<<nodeBlocks, 256, 0, stream>>>(rowStart, srcS, AS1, AD1, Hbf, b1, out1b, N);

  // ---- layer 2 (H=1, C=128): GEMM reads bf16 input directly ----
  gemm_mfma<1, true><<<gemmBlocks, 256, 0, stream>>>(out1b, WT2, Hbf, as2w, ad2w, AS2, AD2, N);
  gat_node<1, false><<<nodeBlocks, 256, 0, stream>>>(rowStart, srcS, AS2, AD2, Hbf, b2, d_out, N);
}